// Round 17
// baseline (174.527 us; speedup 1.0000x reference)
//
#include <hip/hip_runtime.h>
#include <hip/hip_bf16.h>
#include <math.h>

typedef unsigned short u16;
typedef __attribute__((ext_vector_type(8))) short s8v;
typedef __attribute__((ext_vector_type(4))) float f4v;

#define DM 768
#define DL 384

__device__ __forceinline__ u16 f2bf(float f) {
  union { float f; unsigned u; } v; v.f = f;
  unsigned r = v.u + 0x7fffu + ((v.u >> 16) & 1u);
  return (u16)(r >> 16);
}
__device__ __forceinline__ u16 f2bf_rne(float f) {
  return __bfloat16_as_ushort(__float2bfloat16(f));
}

// ---------- builders ----------
__global__ void k_build_c2(const float* __restrict__ kr0, const float* __restrict__ ki0,
                           const float* __restrict__ kr1, const float* __restrict__ ki1,
                           float* __restrict__ c0, float* __restrict__ c1) {
  const float* kr = blockIdx.y ? kr1 : kr0;
  const float* ki = blockIdx.y ? ki1 : ki0;
  float* c = blockIdx.y ? c1 : c0;
  const int t = blockIdx.x;
  const int f = threadIdx.x;
  float s = 0.f;
  for (int ff = f; ff < 384; ff += 256) {
    if (ff >= 1) {
      int ph = (ff * t) % DM;
      float th = (float)ph * (6.283185307179586f / DM);
      float sn, cs; sincosf(th, &sn, &cs);
      s += 2.f * (kr[ff] * cs - ki[ff] * sn);
    }
  }
  if (f == 0) s += kr[0] + ((t & 1) ? -kr[384] : kr[384]);
  __shared__ float red[256];
  red[f] = s; __syncthreads();
  for (int k = 128; k > 0; k >>= 1) {
    if (f < k) red[f] += red[f + k];
    __syncthreads();
  }
  if (f == 0) c[t] = red[0] * (1.f / DM);
}

__device__ __constant__ int   MI_[4][4] = {{0,1,2,3},{1,0,3,2},{2,3,0,1},{3,2,1,0}};
__device__ __constant__ float SG_[4][4] = {{1,-1,-1,-1},{1,1,-1,1},{1,1,1,-1},{1,-1,1,1}};

// merged static builder:
// [0,2304) Benc  [2304,4608) Cdec  [4608,5760) Wenc  [5760,6912) DdT  [6912,6915) rb
__global__ void k_static(const float* __restrict__ c_enc, u16* __restrict__ Benc,
                         const float* __restrict__ c_dec, u16* __restrict__ Cdec,
                         const float* __restrict__ eWw, const float* __restrict__ eWx,
                         const float* __restrict__ eWy, const float* __restrict__ eWz,
                         u16* __restrict__ Wenc,
                         const float* __restrict__ dWw, const float* __restrict__ dWx,
                         const float* __restrict__ dWy, const float* __restrict__ dWz,
                         u16* __restrict__ DdT,
                         const float* __restrict__ dec_b, float* __restrict__ rb) {
  const int b = blockIdx.x;
  const int tt = threadIdx.x;
  if (b < 4608) {
    const float* c = (b < 2304) ? c_enc : c_dec;
    u16* B = (b < 2304) ? Benc : Cdec;
    int idx = (b < 2304 ? b : b - 2304) * 256 + tt;
    int i = idx / DM, j = idx % DM;
    int d = i - j; if (d < 0) d += DM;
    B[idx] = f2bf(c[d]);
  } else if (b < 5760) {
    int idx = (b - 4608) * 256 + tt;
    int o = idx / DM, j = idx % DM;
    int p = o / 96, r = o % 96, q = j / 192, cc = j % 192;
    const float* Ws[4] = {eWw, eWx, eWy, eWz};
    Wenc[idx] = f2bf(SG_[p][q] * Ws[MI_[p][q]][r * 192 + cc]);
  } else if (b < 6912) {
    int idx = (b - 5760) * 256 + tt;
    int o = idx / DM, j = idx % DM;
    int p = j / 192, r = j % 192, q = o / 96, cc = o % 96;
    const float* Ws[4] = {dWw, dWx, dWy, dWz};
    DdT[idx] = f2bf(SG_[p][q] * Ws[MI_[p][q]][r * 96 + cc]);
  } else {
    // rb[i] = sum_j c_dec[(i-j) mod 768] * dec_b[j]; one row per block
    const int i = (b - 6912) * 256 + 0;       // 3 blocks cover 768 rows? No: one block per 256 rows is wrong.
    // each block handles 256 consecutive i values? Too slow serially; instead:
    // blocks 6912..6914 each handle 256 rows, thread tt = row within chunk,
    // serial 768-loop per thread (same cost as old k_rb2 was fine at 768 blocks;
    // here 256 threads each do 768 iters ~ same as k_rb2's per-thread work x1).
    int row = (b - 6912) * 256 + tt;
    float s = 0.f; int ci = row;
    for (int j = 0; j < DM; ++j) { s += c_dec[ci] * dec_b[j]; ci = ci ? ci - 1 : DM - 1; }
    rb[row] = s;
  }
}

__device__ __forceinline__ void ld_lds16(const u16* g, u16* l) {
  __builtin_amdgcn_global_load_lds((const __attribute__((address_space(1))) void*)g,
                                   (__attribute__((address_space(3))) void*)l, 16, 0, 0);
}

// ================= G1: 256x192 8-phase GEMM, fp32-A fused convert, gelu epilogue =====
__global__ __launch_bounds__(512, 1) void gemm8f_g1(
    const float* __restrict__ X, const u16* __restrict__ B, u16* __restrict__ outb) {
  __shared__ __align__(16) u16 SM[57344];
  const int t = threadIdx.x;
  const int lane = t & 63, wid = t >> 6;
  const int wrow = wid >> 2, wcol = wid & 3;
  int wg = blockIdx.x;
  { const int q = gridDim.x >> 3; wg = (wg & 7) * q + (wg >> 3); }
  const int bm = wg >> 2, bn = wg & 3;
  constexpr int KT = 768, NT = 768, NKT = KT / 64;

  f4v acc[8][3];
#pragma unroll
  for (int m = 0; m < 8; ++m)
#pragma unroll
    for (int n = 0; n < 3; ++n) acc[m][n] = (f4v)0.f;

  const int srow = t >> 3;
  const int sgrp = (t & 7) ^ (srow & 7);
  const float* gX = X + (size_t)(bm * 256 + srow) * KT + sgrp * 8;
  const u16*   gB = B + (size_t)(bn * 192 + srow) * KT + sgrp * 8;
  const int sx = ((lane >> 4) ^ (lane & 7)) * 8;
  const int ar = (wrow * 128 + (lane & 15)) * 64;
  const int br = 32768 + (wcol * 48 + (lane & 15)) * 64;

  auto stgB = [&](int kt_, int c_) {
    const u16* g = gB + (size_t)(c_ * 64) * KT + kt_ * 64;
    ld_lds16(g, SM + 32768 + (kt_ & 1) * 12288 + c_ * 4096 + t * 8);
  };
  float4 ra0[4], ra1[4];
  auto LA = [&](int kt_, int half_, float4* r) {
    const float* g = gX + (size_t)(half_ * 128) * KT + kt_ * 64;
    r[0] = *(const float4*)(g);
    r[1] = *(const float4*)(g + 4);
    r[2] = *(const float4*)(g + 64 * KT);
    r[3] = *(const float4*)(g + 64 * KT + 4);
  };
  auto WA = [&](int kt_, int half_, const float4* r) {
    union { u16 u[8]; s8v s; } w0, w1;
    w0.u[0] = f2bf_rne(r[0].x); w0.u[1] = f2bf_rne(r[0].y);
    w0.u[2] = f2bf_rne(r[0].z); w0.u[3] = f2bf_rne(r[0].w);
    w0.u[4] = f2bf_rne(r[1].x); w0.u[5] = f2bf_rne(r[1].y);
    w0.u[6] = f2bf_rne(r[1].z); w0.u[7] = f2bf_rne(r[1].w);
    w1.u[0] = f2bf_rne(r[2].x); w1.u[1] = f2bf_rne(r[2].y);
    w1.u[2] = f2bf_rne(r[2].z); w1.u[3] = f2bf_rne(r[2].w);
    w1.u[4] = f2bf_rne(r[3].x); w1.u[5] = f2bf_rne(r[3].y);
    w1.u[6] = f2bf_rne(r[3].z); w1.u[7] = f2bf_rne(r[3].w);
    u16* l = SM + (kt_ & 1) * 16384 + half_ * 8192 + t * 8;
    *(s8v*)l = w0.s;
    *(s8v*)(l + 4096) = w1.s;
  };

  stgB(0, 0); stgB(0, 1); stgB(0, 2);
  LA(0, 0, ra0); LA(0, 1, ra1);
  asm volatile("s_waitcnt vmcnt(4)" ::: "memory");
  __builtin_amdgcn_sched_barrier(0);
  WA(0, 0, ra0);
  asm volatile("s_waitcnt vmcnt(0)" ::: "memory");
  __builtin_amdgcn_sched_barrier(0);
  WA(0, 1, ra1);
  asm volatile("s_waitcnt lgkmcnt(0)" ::: "memory");
  __builtin_amdgcn_sched_barrier(0);
  __builtin_amdgcn_s_barrier();

#pragma unroll 2
  for (int kt = 0; kt < NKT; ++kt) {
    const int ca = (kt & 1) * 16384;
    const int cbb = (kt & 1) * 12288;
    s8v a0[4][2], a1[4][2], b01[2][2], b2[2];
#pragma unroll
    for (int m = 0; m < 4; ++m) {
      a0[m][0] = *(const s8v*)(SM + ca + ar + m * 1024 + sx);
      a0[m][1] = *(const s8v*)(SM + ca + ar + m * 1024 + (sx ^ 32));
    }
#pragma unroll
    for (int n = 0; n < 2; ++n) {
      b01[n][0] = *(const s8v*)(SM + cbb + br + n * 1024 + sx);
      b01[n][1] = *(const s8v*)(SM + cbb + br + n * 1024 + (sx ^ 32));
    }
    if (kt + 1 < NKT) {
      stgB(kt + 1, 0); stgB(kt + 1, 1); stgB(kt + 1, 2);
      LA(kt + 1, 0, ra0);
    }
    __builtin_amdgcn_s_barrier();
    asm volatile("s_waitcnt lgkmcnt(0)" ::: "memory");
    __builtin_amdgcn_sched_barrier(0);
    __builtin_amdgcn_s_setprio(1);
#pragma unroll
    for (int m = 0; m < 4; ++m)
#pragma unroll
      for (int n = 0; n < 2; ++n) {
        acc[m][n] = __builtin_amdgcn_mfma_f32_16x16x32_bf16(a0[m][0], b01[n][0], acc[m][n], 0, 0, 0);
        acc[m][n] = __builtin_amdgcn_mfma_f32_16x16x32_bf16(a0[m][1], b01[n][1], acc[m][n], 0, 0, 0);
      }
    __builtin_amdgcn_s_setprio(0);
    __builtin_amdgcn_s_barrier();
#pragma unroll
    for (int m = 0; m < 4; ++m) {
      a1[m][0] = *(const s8v*)(SM + ca + ar + (4 + m) * 1024 + sx);
      a1[m][1] = *(const s8v*)(SM + ca + ar + (4 + m) * 1024 + (sx ^ 32));
    }
    if (kt + 1 < NKT) LA(kt + 1, 1, ra1);
    __builtin_amdgcn_s_barrier();
    asm volatile("s_waitcnt lgkmcnt(0)" ::: "memory");
    __builtin_amdgcn_sched_barrier(0);
    __builtin_amdgcn_s_setprio(1);
#pragma unroll
    for (int m = 0; m < 4; ++m)
#pragma unroll
      for (int n = 0; n < 2; ++n) {
        acc[4 + m][n] = __builtin_amdgcn_mfma_f32_16x16x32_bf16(a1[m][0], b01[n][0], acc[4 + m][n], 0, 0, 0);
        acc[4 + m][n] = __builtin_amdgcn_mfma_f32_16x16x32_bf16(a1[m][1], b01[n][1], acc[4 + m][n], 0, 0, 0);
      }
    __builtin_amdgcn_s_setprio(0);
    __builtin_amdgcn_s_barrier();
    b2[0] = *(const s8v*)(SM + cbb + br + 2048 + sx);
    b2[1] = *(const s8v*)(SM + cbb + br + 2048 + (sx ^ 32));
    if (kt + 1 < NKT) {
      asm volatile("s_waitcnt vmcnt(4)" ::: "memory");
      __builtin_amdgcn_sched_barrier(0);
      WA(kt + 1, 0, ra0);
    }
    __builtin_amdgcn_s_barrier();
    asm volatile("s_waitcnt lgkmcnt(0)" ::: "memory");
    __builtin_amdgcn_sched_barrier(0);
    __builtin_amdgcn_s_setprio(1);
#pragma unroll
    for (int m = 0; m < 4; ++m) {
      acc[4 + m][2] = __builtin_amdgcn_mfma_f32_16x16x32_bf16(a1[m][0], b2[0], acc[4 + m][2], 0, 0, 0);
      acc[4 + m][2] = __builtin_amdgcn_mfma_f32_16x16x32_bf16(a1[m][1], b2[1], acc[4 + m][2], 0, 0, 0);
    }
    __builtin_amdgcn_s_setprio(0);
    __builtin_amdgcn_s_barrier();
    if (kt + 1 < NKT) {
      asm volatile("s_waitcnt vmcnt(0)" ::: "memory");
      __builtin_amdgcn_sched_barrier(0);
      WA(kt + 1, 1, ra1);
    }
    __builtin_amdgcn_s_barrier();
    asm volatile("s_waitcnt lgkmcnt(0)" ::: "memory");
    __builtin_amdgcn_sched_barrier(0);
    __builtin_amdgcn_s_setprio(1);
#pragma unroll
    for (int m = 0; m < 4; ++m) {
      acc[m][2] = __builtin_amdgcn_mfma_f32_16x16x32_bf16(a0[m][0], b2[0], acc[m][2], 0, 0, 0);
      acc[m][2] = __builtin_amdgcn_mfma_f32_16x16x32_bf16(a0[m][1], b2[1], acc[m][2], 0, 0, 0);
    }
    __builtin_amdgcn_s_setprio(0);
    __builtin_amdgcn_s_barrier();
  }

  for (int ch = 0; ch < 2; ++ch) {
    if (wrow == ch) {
#pragma unroll
      for (int m = 0; m < 8; ++m)
#pragma unroll
        for (int n = 0; n < 3; ++n)
#pragma unroll
          for (int j = 0; j < 4; ++j) {
            float v = acc[m][n][j];
            float u = v * 0.70710678118f, u2 = u * u;
            float p = u * (1.1283791671f + u2 * (-0.37612638903f +
                      u2 * (0.11283791671f + u2 * (-0.02686617064f))));
            v = 0.5f * v * (1.f + p);
            SM[(m * 16 + (lane >> 4) * 4 + j) * 200 + wcol * 48 + n * 16 + (lane & 15)] = f2bf(v);
          }
    }
    __syncthreads();
#pragma unroll
    for (int it = 0; it < 6; ++it) {
      int idx = it * 512 + t;
      int r = idx / 24, c8 = (idx % 24) * 8;
      s8v vv = *(const s8v*)(SM + r * 200 + c8);
      *(s8v*)(outb + (size_t)(bm * 256 + ch * 128 + r) * NT + bn * 192 + c8) = vv;
    }
    __syncthreads();
  }
}

// ========== 128x128 ring GEMM (3 blocks/CU TLP) ==========
// EPI: 1 = +bias -> fp32 + bf16   2 = +bias -> loss vs fp32 xref   3 = plain bf16
template <int KT, int NT, int NBN, int EPI, int SWZ>
__global__ __launch_bounds__(256, 3) void gemm_ring(
    const u16* __restrict__ A, const u16* __restrict__ B,
    u16* __restrict__ outb, float* __restrict__ outf,
    const float* __restrict__ bias, const float* __restrict__ xref,
    float* __restrict__ partials) {
  __shared__ __align__(16) u16 SMR[24576];
#define As_(b) (SMR + (b) * 4096)
#define Bs_(b) (SMR + 12288 + (b) * 4096)
  const int t = threadIdx.x;
  const int wid = t >> 6, lane = t & 63;
  const int wr = wid >> 1, wc = wid & 1;
  int wg = blockIdx.x;
  if (SWZ) { const int q = gridDim.x >> 3; wg = (wg & 7) * q + (wg >> 3); }
  const int bm = wg / NBN, bn = wg % NBN;

  f4v acc[4][4];
#pragma unroll
  for (int m = 0; m < 4; ++m)
#pragma unroll
    for (int n = 0; n < 4; ++n) acc[m][n] = (f4v)0.f;

  const int sgo = ((t & 3) ^ ((t >> 3) & 3)) * 8;
  const u16* gA = A + (size_t)(bm * 128 + (t >> 2)) * KT + sgo;
  const u16* gB = B + (size_t)(bn * 128 + (t >> 2)) * KT + sgo;
  const int fr = lane & 15;
  const int fo = ((lane >> 4) ^ ((fr >> 1) & 3)) * 8;
  constexpr int NK = KT / 32;

  auto stage = [&](int kt_, int b_) {
    const int ko = kt_ * 32;
    ld_lds16(gA + ko, As_(b_) + wid * 512);
    ld_lds16(gA + ko + 64 * KT, As_(b_) + wid * 512 + 2048);
    ld_lds16(gB + ko, Bs_(b_) + wid * 512);
    ld_lds16(gB + ko + 64 * KT, Bs_(b_) + wid * 512 + 2048);
  };

  stage(0, 0);
  stage(1, 1);
#pragma unroll 3
  for (int kt = 0; kt < NK; ++kt) {
    const int b0 = kt % 3, b2 = (kt + 2) % 3;
    if (kt + 2 < NK) stage(kt + 2, b2);
    const int ahead = NK - 1 - kt;
    if (ahead >= 2)      { asm volatile("s_waitcnt vmcnt(8)" ::: "memory"); }
    else if (ahead == 1) { asm volatile("s_waitcnt vmcnt(4)" ::: "memory"); }
    else                 { asm volatile("s_waitcnt vmcnt(0)" ::: "memory"); }
    __builtin_amdgcn_sched_barrier(0);
    __builtin_amdgcn_s_barrier();
    s8v af[4], bfv[4];
#pragma unroll
    for (int m = 0; m < 4; ++m)
      af[m] = *(const s8v*)(As_(b0) + (wr * 64 + m * 16 + fr) * 32 + fo);
#pragma unroll
    for (int n = 0; n < 4; ++n)
      bfv[n] = *(const s8v*)(Bs_(b0) + (wc * 64 + n * 16 + fr) * 32 + fo);
    asm volatile("s_waitcnt lgkmcnt(0)" ::: "memory");
    __builtin_amdgcn_sched_barrier(0);
    __builtin_amdgcn_s_barrier();
    __builtin_amdgcn_s_setprio(1);
#pragma unroll
    for (int m = 0; m < 4; ++m)
#pragma unroll
      for (int n = 0; n < 4; ++n)
        acc[m][n] = __builtin_amdgcn_mfma_f32_16x16x32_bf16(af[m], bfv[n], acc[m][n], 0, 0, 0);
    __builtin_amdgcn_s_setprio(0);
  }

  const int r0l = wr * 64 + ((lane >> 4) << 2);
  const int c0l = wc * 64 + (lane & 15);

  if constexpr (EPI == 2) {
    float bc[4];
#pragma unroll
    for (int n = 0; n < 4; ++n) bc[n] = bias[bn * 128 + c0l + n * 16];
    float ls = 0.f;
#pragma unroll
    for (int m = 0; m < 4; ++m)
#pragma unroll
      for (int n = 0; n < 4; ++n)
#pragma unroll
        for (int j = 0; j < 4; ++j) {
          size_t row = bm * 128 + r0l + m * 16 + j;
          int col = bn * 128 + c0l + n * 16;
          float v = acc[m][n][j] + bc[n];
          float d = v - xref[row * NT + col];
          ls += d * d;
        }
#pragma unroll
    for (int o = 32; o > 0; o >>= 1) ls += __shfl_down(ls, o);
    float* rw = (float*)SMR;
    if (lane == 0) rw[wid] = ls;
    __syncthreads();
    if (t == 0) partials[blockIdx.x] = rw[0] + rw[1] + rw[2] + rw[3];
  } else {
    u16* Cs = SMR;
    float bc[4];
    if constexpr (EPI == 1) {
#pragma unroll
      for (int n = 0; n < 4; ++n) bc[n] = bias[bn * 128 + c0l + n * 16];
    }
#pragma unroll
    for (int m = 0; m < 4; ++m)
#pragma unroll
      for (int n = 0; n < 4; ++n)
#pragma unroll
        for (int j = 0; j < 4; ++j) {
          float v = acc[m][n][j];
          if constexpr (EPI == 1) {
            v += bc[n];
            outf[(size_t)(bm * 128 + r0l + m * 16 + j) * NT + bn * 128 + c0l + n * 16] = v;
          }
          Cs[(r0l + m * 16 + j) * 130 + c0l + n * 16] = f2bf(v);
        }
    __syncthreads();
#pragma unroll
    for (int s = 0; s < 8; ++s) {
      int idx = (s * 256 + t) * 8;
      int r = idx >> 7, c = idx & 127;
      s8v vv = *(const s8v*)(Cs + r * 130 + c);
      *(s8v*)(outb + (size_t)(bm * 128 + r) * NT + bn * 128 + c) = vv;
    }
  }
#undef As_
#undef Bs_
}

__global__ void k_loss_final(const float* __restrict__ partials, float* __restrict__ out) {
  __shared__ float red[256];
  float s = 0.f;
  for (int i = threadIdx.x; i < 1536; i += 256) s += partials[i];
  red[threadIdx.x] = s; __syncthreads();
  for (int k = 128; k > 0; k >>= 1) {
    if (threadIdx.x < k) red[threadIdx.x] += red[threadIdx.x + k];
    __syncthreads();
  }
  if (threadIdx.x == 0) out[0] = red[0] / 25165824.f;
}

extern "C" void kernel_launch(void* const* d_in, const int* in_sizes, int n_in,
                              void* d_out, int out_size, void* d_ws, size_t ws_size,
                              hipStream_t stream) {
  const float* x      = (const float*)d_in[0];
  const float* enc_kr = (const float*)d_in[1];
  const float* enc_ki = (const float*)d_in[2];
  const float* dec_kr = (const float*)d_in[3];
  const float* dec_ki = (const float*)d_in[4];
  const float* enc_Ww = (const float*)d_in[5];
  const float* enc_Wx = (const float*)d_in[6];
  const float* enc_Wy = (const float*)d_in[7];
  const float* enc_Wz = (const float*)d_in[8];
  const float* enc_b  = (const float*)d_in[9];
  const float* dec_Ww = (const float*)d_in[10];
  const float* dec_Wx = (const float*)d_in[11];
  const float* dec_Wy = (const float*)d_in[12];
  const float* dec_Wz = (const float*)d_in[13];
  const float* dec_b  = (const float*)d_in[14];

  char* ws = (char*)d_ws;
  float* c_enc    = (float*)(ws + 0);
  float* c_dec    = (float*)(ws + 4096);
  float* rb       = (float*)(ws + 8192);
  float* partials = (float*)(ws + 12288);      // 1536 floats
  u16*   Benc     = (u16*)(ws + 20480);        // 768*768*2
  u16*   Wenc     = (u16*)(ws + 1200128);      // 384*768*2
  u16*   Mdec     = (u16*)(ws + 1789952);      // 768*384*2
  u16*   Cdec     = (u16*)(ws + 2379776);      // 768*768*2
  u16*   DdT      = (u16*)(ws + 3559424);      // 384*768*2
  u16*   Zb       = (u16*)(ws + 4149248);      // 32768*384*2
  u16*   H        = (u16*)(ws + 29315072);     // 32768*768*2, ends ~80 MB

  k_build_c2<<<dim3(768, 2), 256, 0, stream>>>(enc_kr, enc_ki, dec_kr, dec_ki, c_enc, c_dec);
  k_static<<<6915, 256, 0, stream>>>(c_enc, Benc, c_dec, Cdec,
                                     enc_Ww, enc_Wx, enc_Wy, enc_Wz, Wenc,
                                     dec_Ww, dec_Wx, dec_Wy, dec_Wz, DdT,
                                     dec_b, rb);
  // Mdec = Cdec @ DdT^T  (768x384, K=768)
  gemm_ring<768, 384, 3, 3, 0><<<18, 256, 0, stream>>>(Cdec, DdT, Mdec, nullptr, nullptr, nullptr, nullptr);

  float* zout = (float*)d_out;
  // GEMM1: H = gelu(x @ Benc^T), convert fused  [8-phase 256x192, grid 512]
  gemm8f_g1<<<512, 512, 0, stream>>>(x, Benc, H);
  // GEMM2: z = H @ Wenc^T + b -> fp32 z + bf16 Zb   [ring, 3 blocks/CU]
  gemm_ring<768, 384, 3, 1, 1><<<768, 256, 0, stream>>>(H, Wenc, Zb, zout, enc_b, nullptr, nullptr);
  // GEMM3: loss: recon = Zb @ Mdec^T + rb, vs x (fp32 ref)   [ring]
  gemm_ring<384, 768, 6, 2, 1><<<1536, 256, 0, stream>>>(Zb, Mdec, nullptr, nullptr, rb, x, partials);
  k_loss_final<<<1, 256, 0, stream>>>(partials, zout + (out_size - 1));
}

// Round 18
// 153.521 us; speedup vs baseline: 1.1368x; 1.1368x over previous
//
#include <hip/hip_runtime.h>
#include <hip/hip_bf16.h>
#include <math.h>

typedef unsigned short u16;
typedef __attribute__((ext_vector_type(8))) short s8v;
typedef __attribute__((ext_vector_type(4))) float f4v;

#define DM 768
#define DL 384

__device__ __forceinline__ u16 f2bf(float f) {
  union { float f; unsigned u; } v; v.f = f;
  unsigned r = v.u + 0x7fffu + ((v.u >> 16) & 1u);
  return (u16)(r >> 16);
}
__device__ __forceinline__ u16 f2bf_rne(float f) {
  return __bfloat16_as_ushort(__float2bfloat16(f));
}

// ---------- builders ----------
__global__ void k_build_c2(const float* __restrict__ kr0, const float* __restrict__ ki0,
                           const float* __restrict__ kr1, const float* __restrict__ ki1,
                           float* __restrict__ c0, float* __restrict__ c1) {
  const float* kr = blockIdx.y ? kr1 : kr0;
  const float* ki = blockIdx.y ? ki1 : ki0;
  float* c = blockIdx.y ? c1 : c0;
  const int t = blockIdx.x;
  const int f = threadIdx.x;
  float s = 0.f;
  for (int ff = f; ff < 384; ff += 256) {
    if (ff >= 1) {
      int ph = (ff * t) % DM;
      float th = (float)ph * (6.283185307179586f / DM);
      float sn, cs; sincosf(th, &sn, &cs);
      s += 2.f * (kr[ff] * cs - ki[ff] * sn);
    }
  }
  if (f == 0) s += kr[0] + ((t & 1) ? -kr[384] : kr[384]);
  __shared__ float red[256];
  red[f] = s; __syncthreads();
  for (int k = 128; k > 0; k >>= 1) {
    if (f < k) red[f] += red[f + k];
    __syncthreads();
  }
  if (f == 0) c[t] = red[0] * (1.f / DM);
}

__global__ void k_rb2(const float* __restrict__ c, const float* __restrict__ b,
                      float* __restrict__ rb) {
  const int i = blockIdx.x;
  const int f = threadIdx.x;
  float s = 0.f;
  for (int j = f; j < DM; j += 256) {
    int ci = i - j; if (ci < 0) ci += DM;
    s += c[ci] * b[j];
  }
  __shared__ float red[256];
  red[f] = s; __syncthreads();
  for (int k = 128; k > 0; k >>= 1) {
    if (f < k) red[f] += red[f + k];
    __syncthreads();
  }
  if (f == 0) rb[i] = red[0];
}

__global__ void k_circ2(const float* __restrict__ c0, u16* __restrict__ B0,
                        const float* __restrict__ c1, u16* __restrict__ B1) {
  const float* c = blockIdx.y ? c1 : c0;
  u16* B = blockIdx.y ? B1 : B0;
  int idx = blockIdx.x * 256 + threadIdx.x;
  int i = idx / DM, j = idx % DM;
  int d = i - j; if (d < 0) d += DM;
  B[idx] = f2bf(c[d]);
}

__device__ __constant__ int   MI_[4][4] = {{0,1,2,3},{1,0,3,2},{2,3,0,1},{3,2,1,0}};
__device__ __constant__ float SG_[4][4] = {{1,-1,-1,-1},{1,1,-1,1},{1,1,1,-1},{1,-1,1,1}};

__global__ void k_wenc(const float* __restrict__ Ww, const float* __restrict__ Wx,
                       const float* __restrict__ Wy, const float* __restrict__ Wz,
                       u16* __restrict__ B) {
  int idx = blockIdx.x * 256 + threadIdx.x;     // 384*768
  int o = idx / DM, j = idx % DM;
  int p = o / 96, r = o % 96, q = j / 192, cc = j % 192;
  const float* Ws[4] = {Ww, Wx, Wy, Wz};
  B[idx] = f2bf(SG_[p][q] * Ws[MI_[p][q]][r * 192 + cc]);
}

__global__ void k_ddecT(const float* __restrict__ Ww, const float* __restrict__ Wx,
                        const float* __restrict__ Wy, const float* __restrict__ Wz,
                        u16* __restrict__ B) {
  int idx = blockIdx.x * 256 + threadIdx.x;     // 384*768
  int o = idx / DM, j = idx % DM;
  int p = j / 192, r = j % 192, q = o / 96, cc = o % 96;
  const float* Ws[4] = {Ww, Wx, Wy, Wz};
  B[idx] = f2bf(SG_[p][q] * Ws[MI_[p][q]][r * 96 + cc]);
}

__device__ __forceinline__ void ld_lds16(const u16* g, u16* l) {
  __builtin_amdgcn_global_load_lds((const __attribute__((address_space(1))) void*)g,
                                   (__attribute__((address_space(3))) void*)l, 16, 0, 0);
}

// ================= G1: 256x192 8-phase GEMM, fp32-A fused convert, gelu epilogue =====
// H[r][n] = gelu(sum_k bf16(x[r][k]) * Benc[n][k]); KT=768, grid 512.
// A path: x fp32 -> regs (ph1/ph2) -> cvt+swizzled ds_write (ph3/ph4, T14 split).
__global__ __launch_bounds__(512, 1) void gemm8f_g1(
    const float* __restrict__ X, const u16* __restrict__ B, u16* __restrict__ outb) {
  __shared__ __align__(16) u16 SM[57344];
  const int t = threadIdx.x;
  const int lane = t & 63, wid = t >> 6;
  const int wrow = wid >> 2, wcol = wid & 3;
  int wg = blockIdx.x;
  { const int q = gridDim.x >> 3; wg = (wg & 7) * q + (wg >> 3); }
  const int bm = wg >> 2, bn = wg & 3;
  constexpr int KT = 768, NT = 768, NKT = KT / 64;

  f4v acc[8][3];
#pragma unroll
  for (int m = 0; m < 8; ++m)
#pragma unroll
    for (int n = 0; n < 3; ++n) acc[m][n] = (f4v)0.f;

  const int srow = t >> 3;
  const int sgrp = (t & 7) ^ (srow & 7);      // pre-swizzled source col-group
  const float* gX = X + (size_t)(bm * 256 + srow) * KT + sgrp * 8;
  const u16*   gB = B + (size_t)(bn * 192 + srow) * KT + sgrp * 8;
  const int sx = ((lane >> 4) ^ (lane & 7)) * 8;
  const int ar = (wrow * 128 + (lane & 15)) * 64;
  const int br = 32768 + (wcol * 48 + (lane & 15)) * 64;

  auto stgB = [&](int kt_, int c_) {
    const u16* g = gB + (size_t)(c_ * 64) * KT + kt_ * 64;
    ld_lds16(g, SM + 32768 + (kt_ & 1) * 12288 + c_ * 4096 + t * 8);
  };
  float4 ra0[4], ra1[4];
  auto LA = [&](int kt_, int half_, float4* r) {       // 4 vmem loads -> regs
    const float* g = gX + (size_t)(half_ * 128) * KT + kt_ * 64;
    r[0] = *(const float4*)(g);
    r[1] = *(const float4*)(g + 4);
    r[2] = *(const float4*)(g + 64 * KT);
    r[3] = *(const float4*)(g + 64 * KT + 4);
  };
  auto WA = [&](int kt_, int half_, const float4* r) { // cvt + 2 ds_write_b128
    union { u16 u[8]; s8v s; } w0, w1;
    w0.u[0] = f2bf_rne(r[0].x); w0.u[1] = f2bf_rne(r[0].y);
    w0.u[2] = f2bf_rne(r[0].z); w0.u[3] = f2bf_rne(r[0].w);
    w0.u[4] = f2bf_rne(r[1].x); w0.u[5] = f2bf_rne(r[1].y);
    w0.u[6] = f2bf_rne(r[1].z); w0.u[7] = f2bf_rne(r[1].w);
    w1.u[0] = f2bf_rne(r[2].x); w1.u[1] = f2bf_rne(r[2].y);
    w1.u[2] = f2bf_rne(r[2].z); w1.u[3] = f2bf_rne(r[2].w);
    w1.u[4] = f2bf_rne(r[3].x); w1.u[5] = f2bf_rne(r[3].y);
    w1.u[6] = f2bf_rne(r[3].z); w1.u[7] = f2bf_rne(r[3].w);
    u16* l = SM + (kt_ & 1) * 16384 + half_ * 8192 + t * 8;
    *(s8v*)l = w0.s;
    *(s8v*)(l + 4096) = w1.s;
  };

  // prologue: tile0 (B via gload_lds, A via reg-stage)
  stgB(0, 0); stgB(0, 1); stgB(0, 2);
  LA(0, 0, ra0); LA(0, 1, ra1);
  asm volatile("s_waitcnt vmcnt(4)" ::: "memory");   // SBx3 + LA(h0) landed
  __builtin_amdgcn_sched_barrier(0);
  WA(0, 0, ra0);
  asm volatile("s_waitcnt vmcnt(0)" ::: "memory");
  __builtin_amdgcn_sched_barrier(0);
  WA(0, 1, ra1);
  asm volatile("s_waitcnt lgkmcnt(0)" ::: "memory");
  __builtin_amdgcn_sched_barrier(0);
  __builtin_amdgcn_s_barrier();

#pragma unroll 2
  for (int kt = 0; kt < NKT; ++kt) {
    const int ca = (kt & 1) * 16384;
    const int cbb = (kt & 1) * 12288;
    s8v a0[4][2], a1[4][2], b01[2][2], b2[2];
    // ---- ph1: read a0,b01; issue SB(kt+1,c0..c2) + LA(kt+1,h0); MFMA a0 x b01
#pragma unroll
    for (int m = 0; m < 4; ++m) {
      a0[m][0] = *(const s8v*)(SM + ca + ar + m * 1024 + sx);
      a0[m][1] = *(const s8v*)(SM + ca + ar + m * 1024 + (sx ^ 32));
    }
#pragma unroll
    for (int n = 0; n < 2; ++n) {
      b01[n][0] = *(const s8v*)(SM + cbb + br + n * 1024 + sx);
      b01[n][1] = *(const s8v*)(SM + cbb + br + n * 1024 + (sx ^ 32));
    }
    if (kt + 1 < NKT) {
      stgB(kt + 1, 0); stgB(kt + 1, 1); stgB(kt + 1, 2);
      LA(kt + 1, 0, ra0);
    }
    __builtin_amdgcn_s_barrier();
    asm volatile("s_waitcnt lgkmcnt(0)" ::: "memory");
    __builtin_amdgcn_sched_barrier(0);
    __builtin_amdgcn_s_setprio(1);
#pragma unroll
    for (int m = 0; m < 4; ++m)
#pragma unroll
      for (int n = 0; n < 2; ++n) {
        acc[m][n] = __builtin_amdgcn_mfma_f32_16x16x32_bf16(a0[m][0], b01[n][0], acc[m][n], 0, 0, 0);
        acc[m][n] = __builtin_amdgcn_mfma_f32_16x16x32_bf16(a0[m][1], b01[n][1], acc[m][n], 0, 0, 0);
      }
    __builtin_amdgcn_s_setprio(0);
    __builtin_amdgcn_s_barrier();
    // ---- ph2: read a1; issue LA(kt+1,h1); MFMA a1 x b01
#pragma unroll
    for (int m = 0; m < 4; ++m) {
      a1[m][0] = *(const s8v*)(SM + ca + ar + (4 + m) * 1024 + sx);
      a1[m][1] = *(const s8v*)(SM + ca + ar + (4 + m) * 1024 + (sx ^ 32));
    }
    if (kt + 1 < NKT) LA(kt + 1, 1, ra1);
    __builtin_amdgcn_s_barrier();
    asm volatile("s_waitcnt lgkmcnt(0)" ::: "memory");
    __builtin_amdgcn_sched_barrier(0);
    __builtin_amdgcn_s_setprio(1);
#pragma unroll
    for (int m = 0; m < 4; ++m)
#pragma unroll
      for (int n = 0; n < 2; ++n) {
        acc[4 + m][n] = __builtin_amdgcn_mfma_f32_16x16x32_bf16(a1[m][0], b01[n][0], acc[4 + m][n], 0, 0, 0);
        acc[4 + m][n] = __builtin_amdgcn_mfma_f32_16x16x32_bf16(a1[m][1], b01[n][1], acc[4 + m][n], 0, 0, 0);
      }
    __builtin_amdgcn_s_setprio(0);
    __builtin_amdgcn_s_barrier();
    // ---- ph3: read b2; vmcnt(4) -> write A(kt+1,h0); MFMA a1 x b2
    b2[0] = *(const s8v*)(SM + cbb + br + 2048 + sx);
    b2[1] = *(const s8v*)(SM + cbb + br + 2048 + (sx ^ 32));
    if (kt + 1 < NKT) {
      asm volatile("s_waitcnt vmcnt(4)" ::: "memory");  // SBx3 + LA(h0) retired
      __builtin_amdgcn_sched_barrier(0);
      WA(kt + 1, 0, ra0);
    }
    __builtin_amdgcn_s_barrier();
    asm volatile("s_waitcnt lgkmcnt(0)" ::: "memory");
    __builtin_amdgcn_sched_barrier(0);
    __builtin_amdgcn_s_setprio(1);
#pragma unroll
    for (int m = 0; m < 4; ++m) {
      acc[4 + m][2] = __builtin_amdgcn_mfma_f32_16x16x32_bf16(a1[m][0], b2[0], acc[4 + m][2], 0, 0, 0);
      acc[4 + m][2] = __builtin_amdgcn_mfma_f32_16x16x32_bf16(a1[m][1], b2[1], acc[4 + m][2], 0, 0, 0);
    }
    __builtin_amdgcn_s_setprio(0);
    __builtin_amdgcn_s_barrier();
    // ---- ph4: vmcnt(0) -> write A(kt+1,h1); MFMA a0 x b2
    if (kt + 1 < NKT) {
      asm volatile("s_waitcnt vmcnt(0)" ::: "memory");  // LA(h1), issued 2 phases ago
      __builtin_amdgcn_sched_barrier(0);
      WA(kt + 1, 1, ra1);
    }
    __builtin_amdgcn_s_barrier();
    asm volatile("s_waitcnt lgkmcnt(0)" ::: "memory");
    __builtin_amdgcn_sched_barrier(0);
    __builtin_amdgcn_s_setprio(1);
#pragma unroll
    for (int m = 0; m < 4; ++m) {
      acc[m][2] = __builtin_amdgcn_mfma_f32_16x16x32_bf16(a0[m][0], b2[0], acc[m][2], 0, 0, 0);
      acc[m][2] = __builtin_amdgcn_mfma_f32_16x16x32_bf16(a0[m][1], b2[1], acc[m][2], 0, 0, 0);
    }
    __builtin_amdgcn_s_setprio(0);
    __builtin_amdgcn_s_barrier();
  }

  // gelu -> bf16, coalesced via LDS (stride 200), two 128-row chunks
  for (int ch = 0; ch < 2; ++ch) {
    if (wrow == ch) {
#pragma unroll
      for (int m = 0; m < 8; ++m)
#pragma unroll
        for (int n = 0; n < 3; ++n)
#pragma unroll
          for (int j = 0; j < 4; ++j) {
            float v = acc[m][n][j];
            float u = v * 0.70710678118f, u2 = u * u;
            float p = u * (1.1283791671f + u2 * (-0.37612638903f +
                      u2 * (0.11283791671f + u2 * (-0.02686617064f))));
            v = 0.5f * v * (1.f + p);
            SM[(m * 16 + (lane >> 4) * 4 + j) * 200 + wcol * 48 + n * 16 + (lane & 15)] = f2bf(v);
          }
    }
    __syncthreads();
#pragma unroll
    for (int it = 0; it < 6; ++it) {
      int idx = it * 512 + t;
      int r = idx / 24, c8 = (idx % 24) * 8;
      s8v vv = *(const s8v*)(SM + r * 200 + c8);
      *(s8v*)(outb + (size_t)(bm * 256 + ch * 128 + r) * NT + bn * 192 + c8) = vv;
    }
    __syncthreads();
  }
}

// ========== 128x128 ring GEMM (3 blocks/CU TLP) ==========
// EPI: 1 = +bias -> fp32 + bf16   2 = +bias -> loss vs fp32 xref   3 = plain bf16
template <int KT, int NT, int NBN, int EPI, int SWZ>
__global__ __launch_bounds__(256, 3) void gemm_ring(
    const u16* __restrict__ A, const u16* __restrict__ B,
    u16* __restrict__ outb, float* __restrict__ outf,
    const float* __restrict__ bias, const float* __restrict__ xref,
    float* __restrict__ partials) {
  __shared__ __align__(16) u16 SMR[24576];
#define As_(b) (SMR + (b) * 4096)
#define Bs_(b) (SMR + 12288 + (b) * 4096)
  const int t = threadIdx.x;
  const int wid = t >> 6, lane = t & 63;
  const int wr = wid >> 1, wc = wid & 1;
  int wg = blockIdx.x;
  if (SWZ) { const int q = gridDim.x >> 3; wg = (wg & 7) * q + (wg >> 3); }
  const int bm = wg / NBN, bn = wg % NBN;

  f4v acc[4][4];
#pragma unroll
  for (int m = 0; m < 4; ++m)
#pragma unroll
    for (int n = 0; n < 4; ++n) acc[m][n] = (f4v)0.f;

  const int sgo = ((t & 3) ^ ((t >> 3) & 3)) * 8;
  const u16* gA = A + (size_t)(bm * 128 + (t >> 2)) * KT + sgo;
  const u16* gB = B + (size_t)(bn * 128 + (t >> 2)) * KT + sgo;
  const int fr = lane & 15;
  const int fo = ((lane >> 4) ^ ((fr >> 1) & 3)) * 8;
  constexpr int NK = KT / 32;

  auto stage = [&](int kt_, int b_) {
    const int ko = kt_ * 32;
    ld_lds16(gA + ko, As_(b_) + wid * 512);
    ld_lds16(gA + ko + 64 * KT, As_(b_) + wid * 512 + 2048);
    ld_lds16(gB + ko, Bs_(b_) + wid * 512);
    ld_lds16(gB + ko + 64 * KT, Bs_(b_) + wid * 512 + 2048);
  };

  stage(0, 0);
  stage(1, 1);
#pragma unroll 3
  for (int kt = 0; kt < NK; ++kt) {
    const int b0 = kt % 3, b2 = (kt + 2) % 3;
    if (kt + 2 < NK) stage(kt + 2, b2);
    const int ahead = NK - 1 - kt;
    if (ahead >= 2)      { asm volatile("s_waitcnt vmcnt(8)" ::: "memory"); }
    else if (ahead == 1) { asm volatile("s_waitcnt vmcnt(4)" ::: "memory"); }
    else                 { asm volatile("s_waitcnt vmcnt(0)" ::: "memory"); }
    __builtin_amdgcn_sched_barrier(0);
    __builtin_amdgcn_s_barrier();
    s8v af[4], bfv[4];
#pragma unroll
    for (int m = 0; m < 4; ++m)
      af[m] = *(const s8v*)(As_(b0) + (wr * 64 + m * 16 + fr) * 32 + fo);
#pragma unroll
    for (int n = 0; n < 4; ++n)
      bfv[n] = *(const s8v*)(Bs_(b0) + (wc * 64 + n * 16 + fr) * 32 + fo);
    asm volatile("s_waitcnt lgkmcnt(0)" ::: "memory");
    __builtin_amdgcn_sched_barrier(0);
    __builtin_amdgcn_s_barrier();
    __builtin_amdgcn_s_setprio(1);
#pragma unroll
    for (int m = 0; m < 4; ++m)
#pragma unroll
      for (int n = 0; n < 4; ++n)
        acc[m][n] = __builtin_amdgcn_mfma_f32_16x16x32_bf16(af[m], bfv[n], acc[m][n], 0, 0, 0);
    __builtin_amdgcn_s_setprio(0);
  }

  const int r0l = wr * 64 + ((lane >> 4) << 2);
  const int c0l = wc * 64 + (lane & 15);

  if constexpr (EPI == 2) {
    float bc[4];
#pragma unroll
    for (int n = 0; n < 4; ++n) bc[n] = bias[bn * 128 + c0l + n * 16];
    float ls = 0.f;
#pragma unroll
    for (int m = 0; m < 4; ++m)
#pragma unroll
      for (int n = 0; n < 4; ++n)
#pragma unroll
        for (int j = 0; j < 4; ++j) {
          size_t row = bm * 128 + r0l + m * 16 + j;
          int col = bn * 128 + c0l + n * 16;
          float v = acc[m][n][j] + bc[n];
          float d = v - xref[row * NT + col];
          ls += d * d;
        }
#pragma unroll
    for (int o = 32; o > 0; o >>= 1) ls += __shfl_down(ls, o);
    float* rw = (float*)SMR;
    if (lane == 0) rw[wid] = ls;
    __syncthreads();
    if (t == 0) partials[blockIdx.x] = rw[0] + rw[1] + rw[2] + rw[3];
  } else {
    u16* Cs = SMR;
    float bc[4];
    if constexpr (EPI == 1) {
#pragma unroll
      for (int n = 0; n < 4; ++n) bc[n] = bias[bn * 128 + c0l + n * 16];
    }
#pragma unroll
    for (int m = 0; m < 4; ++m)
#pragma unroll
      for (int n = 0; n < 4; ++n)
#pragma unroll
        for (int j = 0; j < 4; ++j) {
          float v = acc[m][n][j];
          if constexpr (EPI == 1) {
            v += bc[n];
            outf[(size_t)(bm * 128 + r0l + m * 16 + j) * NT + bn * 128 + c0l + n * 16] = v;
          }
          Cs[(r0l + m * 16 + j) * 130 + c0l + n * 16] = f2bf(v);
        }
    __syncthreads();
#pragma unroll
    for (int s = 0; s < 8; ++s) {
      int idx = (s * 256 + t) * 8;
      int r = idx >> 7, c = idx & 127;
      s8v vv = *(const s8v*)(Cs + r * 130 + c);
      *(s8v*)(outb + (size_t)(bm * 128 + r) * NT + bn * 128 + c) = vv;
    }
  }
#undef As_
#undef Bs_
}

__global__ void k_loss_final(const float* __restrict__ partials, float* __restrict__ out) {
  __shared__ float red[256];
  float s = 0.f;
  for (int i = threadIdx.x; i < 1536; i += 256) s += partials[i];
  red[threadIdx.x] = s; __syncthreads();
  for (int k = 128; k > 0; k >>= 1) {
    if (threadIdx.x < k) red[threadIdx.x] += red[threadIdx.x + k];
    __syncthreads();
  }
  if (threadIdx.x == 0) out[0] = red[0] / 25165824.f;
}

extern "C" void kernel_launch(void* const* d_in, const int* in_sizes, int n_in,
                              void* d_out, int out_size, void* d_ws, size_t ws_size,
                              hipStream_t stream) {
  const float* x      = (const float*)d_in[0];
  const float* enc_kr = (const float*)d_in[1];
  const float* enc_ki = (const float*)d_in[2];
  const float* dec_kr = (const float*)d_in[3];
  const float* dec_ki = (const float*)d_in[4];
  const float* enc_Ww = (const float*)d_in[5];
  const float* enc_Wx = (const float*)d_in[6];
  const float* enc_Wy = (const float*)d_in[7];
  const float* enc_Wz = (const float*)d_in[8];
  const float* enc_b  = (const float*)d_in[9];
  const float* dec_Ww = (const float*)d_in[10];
  const float* dec_Wx = (const float*)d_in[11];
  const float* dec_Wy = (const float*)d_in[12];
  const float* dec_Wz = (const float*)d_in[13];
  const float* dec_b  = (const float*)d_in[14];

  char* ws = (char*)d_ws;
  float* c_enc    = (float*)(ws + 0);
  float* c_dec    = (float*)(ws + 4096);
  float* rb       = (float*)(ws + 8192);
  float* partials = (float*)(ws + 12288);      // 1536 floats
  u16*   Benc     = (u16*)(ws + 20480);        // 768*768*2
  u16*   Wenc     = (u16*)(ws + 1200128);      // 384*768*2
  u16*   Mdec     = (u16*)(ws + 1789952);      // 768*384*2
  u16*   Cdec     = (u16*)(ws + 2379776);      // 768*768*2
  u16*   DdT      = (u16*)(ws + 3559424);      // 384*768*2
  u16*   Zb       = (u16*)(ws + 4149248);      // 32768*384*2
  u16*   H        = (u16*)(ws + 29315072);     // 32768*768*2, ends ~80 MB

  k_build_c2<<<dim3(768, 2), 256, 0, stream>>>(enc_kr, enc_ki, dec_kr, dec_ki, c_enc, c_dec);
  k_rb2<<<768, 256, 0, stream>>>(c_dec, dec_b, rb);
  k_circ2<<<dim3(2304, 2), 256, 0, stream>>>(c_enc, Benc, c_dec, Cdec);
  k_wenc<<<1152, 256, 0, stream>>>(enc_Ww, enc_Wx, enc_Wy, enc_Wz, Wenc);
  k_ddecT<<<1152, 256, 0, stream>>>(dec_Ww, dec_Wx, dec_Wy, dec_Wz, DdT);
  // Mdec = Cdec @ DdT^T  (768x384, K=768)
  gemm_ring<768, 384, 3, 3, 0><<<18, 256, 0, stream>>>(Cdec, DdT, Mdec, nullptr, nullptr, nullptr, nullptr);

  float* zout = (float*)d_out;
  // GEMM1: H = gelu(x @ Benc^T), convert fused  [8-phase 256x192, grid 512]
  gemm8f_g1<<<512, 512, 0, stream>>>(x, Benc, H);
  // GEMM2: z = H @ Wenc^T + b -> fp32 z + bf16 Zb   [ring, 3 blocks/CU]
  gemm_ring<768, 384, 3, 1, 1><<<768, 256, 0, stream>>>(H, Wenc, Zb, zout, enc_b, nullptr, nullptr);
  // GEMM3: loss: recon = Zb @ Mdec^T + rb, vs x (fp32 ref)   [ring]
  gemm_ring<384, 768, 6, 2, 1><<<1536, 256, 0, stream>>>(Zb, Mdec, nullptr, nullptr, rb, x, partials);
  k_loss_final<<<1, 256, 0, stream>>>(partials, zout + (out_size - 1));
}

// Round 19
// 149.690 us; speedup vs baseline: 1.1659x; 1.0256x over previous
//
#include <hip/hip_runtime.h>
#include <hip/hip_bf16.h>
#include <math.h>

typedef unsigned short u16;
typedef __attribute__((ext_vector_type(8))) short s8v;
typedef __attribute__((ext_vector_type(4))) float f4v;

#define DM 768
#define DL 384

__device__ __forceinline__ u16 f2bf(float f) {
  union { float f; unsigned u; } v; v.f = f;
  unsigned r = v.u + 0x7fffu + ((v.u >> 16) & 1u);
  return (u16)(r >> 16);
}
__device__ __forceinline__ u16 f2bf_rne(float f) {
  return __bfloat16_as_ushort(__float2bfloat16(f));
}

// ---------- builders ----------
__global__ void k_build_c2(const float* __restrict__ kr0, const float* __restrict__ ki0,
                           const float* __restrict__ kr1, const float* __restrict__ ki1,
                           float* __restrict__ c0, float* __restrict__ c1) {
  const float* kr = blockIdx.y ? kr1 : kr0;
  const float* ki = blockIdx.y ? ki1 : ki0;
  float* c = blockIdx.y ? c1 : c0;
  const int t = blockIdx.x;
  const int f = threadIdx.x;
  float s = 0.f;
  for (int ff = f; ff < 384; ff += 256) {
    if (ff >= 1) {
      int ph = (ff * t) % DM;
      float th = (float)ph * (6.283185307179586f / DM);
      float sn, cs; sincosf(th, &sn, &cs);
      s += 2.f * (kr[ff] * cs - ki[ff] * sn);
    }
  }
  if (f == 0) s += kr[0] + ((t & 1) ? -kr[384] : kr[384]);
  __shared__ float red[256];
  red[f] = s; __syncthreads();
  for (int k = 128; k > 0; k >>= 1) {
    if (f < k) red[f] += red[f + k];
    __syncthreads();
  }
  if (f == 0) c[t] = red[0] * (1.f / DM);
}

__device__ __constant__ int   MI_[4][4] = {{0,1,2,3},{1,0,3,2},{2,3,0,1},{3,2,1,0}};
__device__ __constant__ float SG_[4][4] = {{1,-1,-1,-1},{1,1,-1,1},{1,1,1,-1},{1,-1,1,1}};

// merged static builder (all sections fully parallel):
// [0,2304) Benc   [2304,4608) Cdec   [4608,5760) Wenc   [5760,6912) DdT
// [6912,7680) rb: ONE ROW PER BLOCK, 256-thread strided dot + block reduce (no stragglers)
__global__ void k_static2(const float* __restrict__ c_enc, u16* __restrict__ Benc,
                          const float* __restrict__ c_dec, u16* __restrict__ Cdec,
                          const float* __restrict__ eWw, const float* __restrict__ eWx,
                          const float* __restrict__ eWy, const float* __restrict__ eWz,
                          u16* __restrict__ Wenc,
                          const float* __restrict__ dWw, const float* __restrict__ dWx,
                          const float* __restrict__ dWy, const float* __restrict__ dWz,
                          u16* __restrict__ DdT,
                          const float* __restrict__ dec_b, float* __restrict__ rb) {
  const int b = blockIdx.x;
  const int tt = threadIdx.x;
  __shared__ float red[256];
  if (b < 4608) {
    const float* c = (b < 2304) ? c_enc : c_dec;
    u16* B = (b < 2304) ? Benc : Cdec;
    int idx = (b < 2304 ? b : b - 2304) * 256 + tt;
    int i = idx / DM, j = idx % DM;
    int d = i - j; if (d < 0) d += DM;
    B[idx] = f2bf(c[d]);
  } else if (b < 5760) {
    int idx = (b - 4608) * 256 + tt;
    int o = idx / DM, j = idx % DM;
    int p = o / 96, r = o % 96, q = j / 192, cc = j % 192;
    const float* Ws[4] = {eWw, eWx, eWy, eWz};
    Wenc[idx] = f2bf(SG_[p][q] * Ws[MI_[p][q]][r * 192 + cc]);
  } else if (b < 6912) {
    int idx = (b - 5760) * 256 + tt;
    int o = idx / DM, j = idx % DM;
    int p = j / 192, r = j % 192, q = o / 96, cc = o % 96;
    const float* Ws[4] = {dWw, dWx, dWy, dWz};
    DdT[idx] = f2bf(SG_[p][q] * Ws[MI_[p][q]][r * 96 + cc]);
  } else {
    const int i = b - 6912;                       // rb row, k_rb2 pattern
    float s = 0.f;
    for (int j = tt; j < DM; j += 256) {
      int ci = i - j; if (ci < 0) ci += DM;
      s += c_dec[ci] * dec_b[j];
    }
    red[tt] = s; __syncthreads();
    for (int k = 128; k > 0; k >>= 1) {
      if (tt < k) red[tt] += red[tt + k];
      __syncthreads();
    }
    if (tt == 0) rb[i] = red[0];
  }
}

__device__ __forceinline__ void ld_lds16(const u16* g, u16* l) {
  __builtin_amdgcn_global_load_lds((const __attribute__((address_space(1))) void*)g,
                                   (__attribute__((address_space(3))) void*)l, 16, 0, 0);
}

// ================= G1: 256x192 8-phase GEMM, fp32-A fused convert, gelu epilogue =====
// H[r][n] = gelu(sum_k bf16(x[r][k]) * Benc[n][k]); KT=768, grid 512.
// A path: x fp32 -> regs (ph1/ph2) -> cvt+swizzled ds_write (ph3/ph4, T14 split).
__global__ __launch_bounds__(512, 1) void gemm8f_g1(
    const float* __restrict__ X, const u16* __restrict__ B, u16* __restrict__ outb) {
  __shared__ __align__(16) u16 SM[57344];
  const int t = threadIdx.x;
  const int lane = t & 63, wid = t >> 6;
  const int wrow = wid >> 2, wcol = wid & 3;
  int wg = blockIdx.x;
  { const int q = gridDim.x >> 3; wg = (wg & 7) * q + (wg >> 3); }
  const int bm = wg >> 2, bn = wg & 3;
  constexpr int KT = 768, NT = 768, NKT = KT / 64;

  f4v acc[8][3];
#pragma unroll
  for (int m = 0; m < 8; ++m)
#pragma unroll
    for (int n = 0; n < 3; ++n) acc[m][n] = (f4v)0.f;

  const int srow = t >> 3;
  const int sgrp = (t & 7) ^ (srow & 7);      // pre-swizzled source col-group
  const float* gX = X + (size_t)(bm * 256 + srow) * KT + sgrp * 8;
  const u16*   gB = B + (size_t)(bn * 192 + srow) * KT + sgrp * 8;
  const int sx = ((lane >> 4) ^ (lane & 7)) * 8;
  const int ar = (wrow * 128 + (lane & 15)) * 64;
  const int br = 32768 + (wcol * 48 + (lane & 15)) * 64;

  auto stgB = [&](int kt_, int c_) {
    const u16* g = gB + (size_t)(c_ * 64) * KT + kt_ * 64;
    ld_lds16(g, SM + 32768 + (kt_ & 1) * 12288 + c_ * 4096 + t * 8);
  };
  float4 ra0[4], ra1[4];
  auto LA = [&](int kt_, int half_, float4* r) {       // 4 vmem loads -> regs
    const float* g = gX + (size_t)(half_ * 128) * KT + kt_ * 64;
    r[0] = *(const float4*)(g);
    r[1] = *(const float4*)(g + 4);
    r[2] = *(const float4*)(g + 64 * KT);
    r[3] = *(const float4*)(g + 64 * KT + 4);
  };
  auto WA = [&](int kt_, int half_, const float4* r) { // cvt + 2 ds_write_b128
    union { u16 u[8]; s8v s; } w0, w1;
    w0.u[0] = f2bf_rne(r[0].x); w0.u[1] = f2bf_rne(r[0].y);
    w0.u[2] = f2bf_rne(r[0].z); w0.u[3] = f2bf_rne(r[0].w);
    w0.u[4] = f2bf_rne(r[1].x); w0.u[5] = f2bf_rne(r[1].y);
    w0.u[6] = f2bf_rne(r[1].z); w0.u[7] = f2bf_rne(r[1].w);
    w1.u[0] = f2bf_rne(r[2].x); w1.u[1] = f2bf_rne(r[2].y);
    w1.u[2] = f2bf_rne(r[2].z); w1.u[3] = f2bf_rne(r[2].w);
    w1.u[4] = f2bf_rne(r[3].x); w1.u[5] = f2bf_rne(r[3].y);
    w1.u[6] = f2bf_rne(r[3].z); w1.u[7] = f2bf_rne(r[3].w);
    u16* l = SM + (kt_ & 1) * 16384 + half_ * 8192 + t * 8;
    *(s8v*)l = w0.s;
    *(s8v*)(l + 4096) = w1.s;
  };

  // prologue: tile0 (B via gload_lds, A via reg-stage)
  stgB(0, 0); stgB(0, 1); stgB(0, 2);
  LA(0, 0, ra0); LA(0, 1, ra1);
  asm volatile("s_waitcnt vmcnt(4)" ::: "memory");   // SBx3 + LA(h0) landed
  __builtin_amdgcn_sched_barrier(0);
  WA(0, 0, ra0);
  asm volatile("s_waitcnt vmcnt(0)" ::: "memory");
  __builtin_amdgcn_sched_barrier(0);
  WA(0, 1, ra1);
  asm volatile("s_waitcnt lgkmcnt(0)" ::: "memory");
  __builtin_amdgcn_sched_barrier(0);
  __builtin_amdgcn_s_barrier();

#pragma unroll 2
  for (int kt = 0; kt < NKT; ++kt) {
    const int ca = (kt & 1) * 16384;
    const int cbb = (kt & 1) * 12288;
    s8v a0[4][2], a1[4][2], b01[2][2], b2[2];
    // ---- ph1: read a0,b01; issue SB(kt+1,c0..c2) + LA(kt+1,h0); MFMA a0 x b01
#pragma unroll
    for (int m = 0; m < 4; ++m) {
      a0[m][0] = *(const s8v*)(SM + ca + ar + m * 1024 + sx);
      a0[m][1] = *(const s8v*)(SM + ca + ar + m * 1024 + (sx ^ 32));
    }
#pragma unroll
    for (int n = 0; n < 2; ++n) {
      b01[n][0] = *(const s8v*)(SM + cbb + br + n * 1024 + sx);
      b01[n][1] = *(const s8v*)(SM + cbb + br + n * 1024 + (sx ^ 32));
    }
    if (kt + 1 < NKT) {
      stgB(kt + 1, 0); stgB(kt + 1, 1); stgB(kt + 1, 2);
      LA(kt + 1, 0, ra0);
    }
    __builtin_amdgcn_s_barrier();
    asm volatile("s_waitcnt lgkmcnt(0)" ::: "memory");
    __builtin_amdgcn_sched_barrier(0);
    __builtin_amdgcn_s_setprio(1);
#pragma unroll
    for (int m = 0; m < 4; ++m)
#pragma unroll
      for (int n = 0; n < 2; ++n) {
        acc[m][n] = __builtin_amdgcn_mfma_f32_16x16x32_bf16(a0[m][0], b01[n][0], acc[m][n], 0, 0, 0);
        acc[m][n] = __builtin_amdgcn_mfma_f32_16x16x32_bf16(a0[m][1], b01[n][1], acc[m][n], 0, 0, 0);
      }
    __builtin_amdgcn_s_setprio(0);
    __builtin_amdgcn_s_barrier();
    // ---- ph2: read a1; issue LA(kt+1,h1); MFMA a1 x b01
#pragma unroll
    for (int m = 0; m < 4; ++m) {
      a1[m][0] = *(const s8v*)(SM + ca + ar + (4 + m) * 1024 + sx);
      a1[m][1] = *(const s8v*)(SM + ca + ar + (4 + m) * 1024 + (sx ^ 32));
    }
    if (kt + 1 < NKT) LA(kt + 1, 1, ra1);
    __builtin_amdgcn_s_barrier();
    asm volatile("s_waitcnt lgkmcnt(0)" ::: "memory");
    __builtin_amdgcn_sched_barrier(0);
    __builtin_amdgcn_s_setprio(1);
#pragma unroll
    for (int m = 0; m < 4; ++m)
#pragma unroll
      for (int n = 0; n < 2; ++n) {
        acc[4 + m][n] = __builtin_amdgcn_mfma_f32_16x16x32_bf16(a1[m][0], b01[n][0], acc[4 + m][n], 0, 0, 0);
        acc[4 + m][n] = __builtin_amdgcn_mfma_f32_16x16x32_bf16(a1[m][1], b01[n][1], acc[4 + m][n], 0, 0, 0);
      }
    __builtin_amdgcn_s_setprio(0);
    __builtin_amdgcn_s_barrier();
    // ---- ph3: read b2; vmcnt(4) -> write A(kt+1,h0); MFMA a1 x b2
    b2[0] = *(const s8v*)(SM + cbb + br + 2048 + sx);
    b2[1] = *(const s8v*)(SM + cbb + br + 2048 + (sx ^ 32));
    if (kt + 1 < NKT) {
      asm volatile("s_waitcnt vmcnt(4)" ::: "memory");  // SBx3 + LA(h0) retired
      __builtin_amdgcn_sched_barrier(0);
      WA(kt + 1, 0, ra0);
    }
    __builtin_amdgcn_s_barrier();
    asm volatile("s_waitcnt lgkmcnt(0)" ::: "memory");
    __builtin_amdgcn_sched_barrier(0);
    __builtin_amdgcn_s_setprio(1);
#pragma unroll
    for (int m = 0; m < 4; ++m) {
      acc[4 + m][2] = __builtin_amdgcn_mfma_f32_16x16x32_bf16(a1[m][0], b2[0], acc[4 + m][2], 0, 0, 0);
      acc[4 + m][2] = __builtin_amdgcn_mfma_f32_16x16x32_bf16(a1[m][1], b2[1], acc[4 + m][2], 0, 0, 0);
    }
    __builtin_amdgcn_s_setprio(0);
    __builtin_amdgcn_s_barrier();
    // ---- ph4: vmcnt(0) -> write A(kt+1,h1); MFMA a0 x b2
    if (kt + 1 < NKT) {
      asm volatile("s_waitcnt vmcnt(0)" ::: "memory");  // LA(h1), issued 2 phases ago
      __builtin_amdgcn_sched_barrier(0);
      WA(kt + 1, 1, ra1);
    }
    __builtin_amdgcn_s_barrier();
    asm volatile("s_waitcnt lgkmcnt(0)" ::: "memory");
    __builtin_amdgcn_sched_barrier(0);
    __builtin_amdgcn_s_setprio(1);
#pragma unroll
    for (int m = 0; m < 4; ++m) {
      acc[m][2] = __builtin_amdgcn_mfma_f32_16x16x32_bf16(a0[m][0], b2[0], acc[m][2], 0, 0, 0);
      acc[m][2] = __builtin_amdgcn_mfma_f32_16x16x32_bf16(a0[m][1], b2[1], acc[m][2], 0, 0, 0);
    }
    __builtin_amdgcn_s_setprio(0);
    __builtin_amdgcn_s_barrier();
  }

  // gelu -> bf16, coalesced via LDS (stride 200), two 128-row chunks
  for (int ch = 0; ch < 2; ++ch) {
    if (wrow == ch) {
#pragma unroll
      for (int m = 0; m < 8; ++m)
#pragma unroll
        for (int n = 0; n < 3; ++n)
#pragma unroll
          for (int j = 0; j < 4; ++j) {
            float v = acc[m][n][j];
            float u = v * 0.70710678118f, u2 = u * u;
            float p = u * (1.1283791671f + u2 * (-0.37612638903f +
                      u2 * (0.11283791671f + u2 * (-0.02686617064f))));
            v = 0.5f * v * (1.f + p);
            SM[(m * 16 + (lane >> 4) * 4 + j) * 200 + wcol * 48 + n * 16 + (lane & 15)] = f2bf(v);
          }
    }
    __syncthreads();
#pragma unroll
    for (int it = 0; it < 6; ++it) {
      int idx = it * 512 + t;
      int r = idx / 24, c8 = (idx % 24) * 8;
      s8v vv = *(const s8v*)(SM + r * 200 + c8);
      *(s8v*)(outb + (size_t)(bm * 256 + ch * 128 + r) * NT + bn * 192 + c8) = vv;
    }
    __syncthreads();
  }
}

// ========== 128x128 ring GEMM (3 blocks/CU TLP) ==========
// EPI: 1 = +bias -> fp32 + bf16   2 = +bias -> loss vs fp32 xref   3 = plain bf16
template <int KT, int NT, int NBN, int EPI, int SWZ>
__global__ __launch_bounds__(256, 3) void gemm_ring(
    const u16* __restrict__ A, const u16* __restrict__ B,
    u16* __restrict__ outb, float* __restrict__ outf,
    const float* __restrict__ bias, const float* __restrict__ xref,
    float* __restrict__ partials) {
  __shared__ __align__(16) u16 SMR[24576];
#define As_(b) (SMR + (b) * 4096)
#define Bs_(b) (SMR + 12288 + (b) * 4096)
  const int t = threadIdx.x;
  const int wid = t >> 6, lane = t & 63;
  const int wr = wid >> 1, wc = wid & 1;
  int wg = blockIdx.x;
  if (SWZ) { const int q = gridDim.x >> 3; wg = (wg & 7) * q + (wg >> 3); }
  const int bm = wg / NBN, bn = wg % NBN;

  f4v acc[4][4];
#pragma unroll
  for (int m = 0; m < 4; ++m)
#pragma unroll
    for (int n = 0; n < 4; ++n) acc[m][n] = (f4v)0.f;

  const int sgo = ((t & 3) ^ ((t >> 3) & 3)) * 8;
  const u16* gA = A + (size_t)(bm * 128 + (t >> 2)) * KT + sgo;
  const u16* gB = B + (size_t)(bn * 128 + (t >> 2)) * KT + sgo;
  const int fr = lane & 15;
  const int fo = ((lane >> 4) ^ ((fr >> 1) & 3)) * 8;
  constexpr int NK = KT / 32;

  auto stage = [&](int kt_, int b_) {
    const int ko = kt_ * 32;
    ld_lds16(gA + ko, As_(b_) + wid * 512);
    ld_lds16(gA + ko + 64 * KT, As_(b_) + wid * 512 + 2048);
    ld_lds16(gB + ko, Bs_(b_) + wid * 512);
    ld_lds16(gB + ko + 64 * KT, Bs_(b_) + wid * 512 + 2048);
  };

  stage(0, 0);
  stage(1, 1);
#pragma unroll 3
  for (int kt = 0; kt < NK; ++kt) {
    const int b0 = kt % 3, b2 = (kt + 2) % 3;
    if (kt + 2 < NK) stage(kt + 2, b2);
    const int ahead = NK - 1 - kt;
    if (ahead >= 2)      { asm volatile("s_waitcnt vmcnt(8)" ::: "memory"); }
    else if (ahead == 1) { asm volatile("s_waitcnt vmcnt(4)" ::: "memory"); }
    else                 { asm volatile("s_waitcnt vmcnt(0)" ::: "memory"); }
    __builtin_amdgcn_sched_barrier(0);
    __builtin_amdgcn_s_barrier();
    s8v af[4], bfv[4];
#pragma unroll
    for (int m = 0; m < 4; ++m)
      af[m] = *(const s8v*)(As_(b0) + (wr * 64 + m * 16 + fr) * 32 + fo);
#pragma unroll
    for (int n = 0; n < 4; ++n)
      bfv[n] = *(const s8v*)(Bs_(b0) + (wc * 64 + n * 16 + fr) * 32 + fo);
    asm volatile("s_waitcnt lgkmcnt(0)" ::: "memory");
    __builtin_amdgcn_sched_barrier(0);
    __builtin_amdgcn_s_barrier();
    __builtin_amdgcn_s_setprio(1);
#pragma unroll
    for (int m = 0; m < 4; ++m)
#pragma unroll
      for (int n = 0; n < 4; ++n)
        acc[m][n] = __builtin_amdgcn_mfma_f32_16x16x32_bf16(af[m], bfv[n], acc[m][n], 0, 0, 0);
    __builtin_amdgcn_s_setprio(0);
  }

  const int r0l = wr * 64 + ((lane >> 4) << 2);
  const int c0l = wc * 64 + (lane & 15);

  if constexpr (EPI == 2) {
    float bc[4];
#pragma unroll
    for (int n = 0; n < 4; ++n) bc[n] = bias[bn * 128 + c0l + n * 16];
    float ls = 0.f;
#pragma unroll
    for (int m = 0; m < 4; ++m)
#pragma unroll
      for (int n = 0; n < 4; ++n)
#pragma unroll
        for (int j = 0; j < 4; ++j) {
          size_t row = bm * 128 + r0l + m * 16 + j;
          int col = bn * 128 + c0l + n * 16;
          float v = acc[m][n][j] + bc[n];
          float d = v - xref[row * NT + col];
          ls += d * d;
        }
#pragma unroll
    for (int o = 32; o > 0; o >>= 1) ls += __shfl_down(ls, o);
    float* rw = (float*)SMR;
    if (lane == 0) rw[wid] = ls;
    __syncthreads();
    if (t == 0) partials[blockIdx.x] = rw[0] + rw[1] + rw[2] + rw[3];
  } else {
    u16* Cs = SMR;
    float bc[4];
    if constexpr (EPI == 1) {
#pragma unroll
      for (int n = 0; n < 4; ++n) bc[n] = bias[bn * 128 + c0l + n * 16];
    }
#pragma unroll
    for (int m = 0; m < 4; ++m)
#pragma unroll
      for (int n = 0; n < 4; ++n)
#pragma unroll
        for (int j = 0; j < 4; ++j) {
          float v = acc[m][n][j];
          if constexpr (EPI == 1) {
            v += bc[n];
            outf[(size_t)(bm * 128 + r0l + m * 16 + j) * NT + bn * 128 + c0l + n * 16] = v;
          }
          Cs[(r0l + m * 16 + j) * 130 + c0l + n * 16] = f2bf(v);
        }
    __syncthreads();
#pragma unroll
    for (int s = 0; s < 8; ++s) {
      int idx = (s * 256 + t) * 8;
      int r = idx >> 7, c = idx & 127;
      s8v vv = *(const s8v*)(Cs + r * 130 + c);
      *(s8v*)(outb + (size_t)(bm * 128 + r) * NT + bn * 128 + c) = vv;
    }
  }
#undef As_
#undef Bs_
}

__global__ void k_loss_final(const float* __restrict__ partials, float* __restrict__ out) {
  __shared__ float red[256];
  float s = 0.f;
  for (int i = threadIdx.x; i < 1536; i += 256) s += partials[i];
  red[threadIdx.x] = s; __syncthreads();
  for (int k = 128; k > 0; k >>= 1) {
    if (threadIdx.x < k) red[threadIdx.x] += red[threadIdx.x + k];
    __syncthreads();
  }
  if (threadIdx.x == 0) out[0] = red[0] / 25165824.f;
}

extern "C" void kernel_launch(void* const* d_in, const int* in_sizes, int n_in,
                              void* d_out, int out_size, void* d_ws, size_t ws_size,
                              hipStream_t stream) {
  const float* x      = (const float*)d_in[0];
  const float* enc_kr = (const float*)d_in[1];
  const float* enc_ki = (const float*)d_in[2];
  const float* dec_kr = (const float*)d_in[3];
  const float* dec_ki = (const float*)d_in[4];
  const float* enc_Ww = (const float*)d_in[5];
  const float* enc_Wx = (const float*)d_in[6];
  const float* enc_Wy = (const float*)d_in[7];
  const float* enc_Wz = (const float*)d_in[8];
  const float* enc_b  = (const float*)d_in[9];
  const float* dec_Ww = (const float*)d_in[10];
  const float* dec_Wx = (const float*)d_in[11];
  const float* dec_Wy = (const float*)d_in[12];
  const float* dec_Wz = (const float*)d_in[13];
  const float* dec_b  = (const float*)d_in[14];

  char* ws = (char*)d_ws;
  float* c_enc    = (float*)(ws + 0);
  float* c_dec    = (float*)(ws + 4096);
  float* rb       = (float*)(ws + 8192);
  float* partials = (float*)(ws + 12288);      // 1536 floats
  u16*   Benc     = (u16*)(ws + 20480);        // 768*768*2
  u16*   Wenc     = (u16*)(ws + 1200128);      // 384*768*2
  u16*   Mdec     = (u16*)(ws + 1789952);      // 768*384*2
  u16*   Cdec     = (u16*)(ws + 2379776);      // 768*768*2
  u16*   DdT      = (u16*)(ws + 3559424);      // 384*768*2
  u16*   Zb       = (u16*)(ws + 4149248);      // 32768*384*2
  u16*   H        = (u16*)(ws + 29315072);     // 32768*768*2, ends ~80 MB

  k_build_c2<<<dim3(768, 2), 256, 0, stream>>>(enc_kr, enc_ki, dec_kr, dec_ki, c_enc, c_dec);
  k_static2<<<7680, 256, 0, stream>>>(c_enc, Benc, c_dec, Cdec,
                                      enc_Ww, enc_Wx, enc_Wy, enc_Wz, Wenc,
                                      dec_Ww, dec_Wx, dec_Wy, dec_Wz, DdT,
                                      dec_b, rb);
  // Mdec = Cdec @ DdT^T  (768x384, K=768)
  gemm_ring<768, 384, 3, 3, 0><<<18, 256, 0, stream>>>(Cdec, DdT, Mdec, nullptr, nullptr, nullptr, nullptr);

  float* zout = (float*)d_out;
  // GEMM1: H = gelu(x @ Benc^T), convert fused  [8-phase 256x192, grid 512]
  gemm8f_g1<<<512, 512, 0, stream>>>(x, Benc, H);
  // GEMM2: z = H @ Wenc^T + b -> fp32 z + bf16 Zb   [ring, 3 blocks/CU]
  gemm_ring<768, 384, 3, 1, 1><<<768, 256, 0, stream>>>(H, Wenc, Zb, zout, enc_b, nullptr, nullptr);
  // GEMM3: loss: recon = Zb @ Mdec^T + rb, vs x (fp32 ref)   [ring]
  gemm_ring<384, 768, 6, 2, 1><<<1536, 256, 0, stream>>>(Zb, Mdec, nullptr, nullptr, rb, x, partials);
  k_loss_final<<<1, 256, 0, stream>>>(partials, zout + (out_size - 1));
}